// Round 2
// baseline (614.369 us; speedup 1.0000x reference)
//
#include <hip/hip_runtime.h>

// SS2D (VMamba selective scan 2D), dtype-robust (bf16 or fp32 inputs/outputs).
// All intermediates fp32 in d_ws. ws usage: 9,021,060 floats = 36.1 MB.
#define B_  2
#define H_  56
#define W_  56
#define C_  128
#define DIN 256
#define NS  16
#define RR  8
#define KK  4
#define LL  3136
#define CD  40      // R + 2N
#define PC  64      // scan chunks
#define LC  49      // L / PC

// converted-input (fp32) region offsets, cumulative, in floats
#define OFF_X    0
#define OFF_IPW  802816
#define OFF_IPB  868352
#define OFF_CW   868864
#define OFF_CB   871168
#define OFF_XPW  871424
#define OFF_DTW  912384
#define OFF_DTB  920576
#define OFF_ALG  921600
#define OFF_DSS  937984
#define OFF_ONW  939008
#define OFF_ONB  939264
#define OFF_OPW  939520
#define OFF_OPB  972288
#define F_TOTAL  972416

// workspace regions, in floats
#define WOFF_XC    972416       // 1,605,632
#define WOFF_Z     2578048      // 1,605,632
#define WOFF_Y     4183680      // 1,605,632
#define WOFF_XDBL  5789312      // 1,003,520
#define WOFF_SEND  6792832      // 2,097,152 (xh aliases this region)
#define WOFF_DSUM  8889984      //   131,072
#define WOFF_FLAG  9021056      // 1 int

__device__ __forceinline__ float bf2f(unsigned int h){
    return __uint_as_float((h & 0xffffu) << 16);
}
__device__ __forceinline__ unsigned short f2bf(float f){
    unsigned int u = __float_as_uint(f);
    u += 0x7fffu + ((u >> 16) & 1u);
    return (unsigned short)(u >> 16);
}
__device__ __forceinline__ float siluf(float x){ return x / (1.f + __expf(-x)); }

// scan-order -> spatial index (also the y-target position for pass B)
__device__ __forceinline__ int sidx(int k, int l){
    int j = (k < 2) ? l : (LL - 1 - l);
    if ((k & 1) == 0) return j;                 // row-major scan
    return (j % H_) * W_ + (j / H_);            // col-major scan
}

// ---------------- K0a: detect input dtype ----------------------------------
// bf16 activations: |v| <= ~5. fp32 bits read as bf16: even-index shorts are
// mantissa fragments with ~uniform exponent byte -> >1e6 w.p. ~1 in 256 reads.
__global__ void k_detect(const unsigned short* __restrict__ x, int* __restrict__ flag){
    __shared__ float m[256];
    int t = threadIdx.x;
    m[t] = fabsf(bf2f(x[t]));
    __syncthreads();
    if (t == 0){
        float mx = 0.f;
        for (int i = 0; i < 256; ++i) mx = fmaxf(mx, m[i]);
        *flag = (mx > 1e6f) ? 1 : 0;
    }
}

// ---------------- K0b: convert all inputs to fp32 region F ------------------
struct CvtArgs { const void* src[14]; int off[15]; };

__global__ __launch_bounds__(256) void k_convert(CvtArgs a, const int* __restrict__ flag,
                                                 float* __restrict__ F){
    int g = blockIdx.x*256 + threadIdx.x;
    if (g >= F_TOTAL) return;
    int seg = 0;
    #pragma unroll
    for (int i = 1; i < 14; ++i) seg += (g >= a.off[i]);
    int i0 = g - a.off[seg];
    float v;
    if (*flag) v = ((const float*)a.src[seg])[i0];
    else       v = bf2f(((const unsigned short*)a.src[seg])[i0]);
    F[g] = v;
}

// ---------------- K1: in_proj (x @ W^T + b) -> xh / silu(z) -----------------
__global__ __launch_bounds__(512) void k_inproj(
        const float* __restrict__ F, float* __restrict__ xh, float* __restrict__ z){
    const float* x    = F + OFF_X;
    const float* w    = F + OFF_IPW;
    const float* bias = F + OFF_IPB;
    int bl = blockIdx.x;            // b*L + l
    int t  = threadIdx.x;           // 0..511 = e
    __shared__ __align__(16) float xrow[C_];
    if (t < C_) xrow[t] = x[bl*C_ + t];
    __syncthreads();
    const float4* w4  = reinterpret_cast<const float4*>(w + t*C_);
    const float4* xr4 = reinterpret_cast<const float4*>(xrow);
    float acc = bias[t];
    #pragma unroll
    for (int c4 = 0; c4 < C_/4; ++c4){
        float4 wv = w4[c4], xv = xr4[c4];
        acc = fmaf(wv.x, xv.x, acc); acc = fmaf(wv.y, xv.y, acc);
        acc = fmaf(wv.z, xv.z, acc); acc = fmaf(wv.w, xv.w, acc);
    }
    if (t < DIN) xh[bl*DIN + t] = acc;
    else         z[bl*DIN + (t - DIN)] = siluf(acc);
}

// ---------------- K2: depthwise 3x3 conv + silu (NHWC) ----------------------
__global__ __launch_bounds__(256) void k_conv(
        const float* __restrict__ F, const float* __restrict__ xh,
        float* __restrict__ xc){
    const float* cw = F + OFF_CW;
    const float* cb = F + OFF_CB;
    int bl = blockIdx.x; int b = bl / LL; int s = bl % LL;
    int h = s / W_, w = s % W_;
    int d = threadIdx.x;
    float acc = cb[d];
    #pragma unroll
    for (int i = 0; i < 3; ++i){
        int nh = h + i - 1;
        if (nh < 0 || nh >= H_) continue;
        #pragma unroll
        for (int j = 0; j < 3; ++j){
            int nw = w + j - 1;
            if (nw < 0 || nw >= W_) continue;
            acc = fmaf(xh[(b*LL + nh*W_ + nw)*DIN + d], cw[d*9 + i*3 + j], acc);
        }
    }
    xc[bl*DIN + d] = siluf(acc);
}

// ---------------- K3: x_proj -> xdbl (B,K,L,40) = [dts(8) | B(16) | C(16)] --
__global__ __launch_bounds__(64) void k_xproj(
        const float* __restrict__ F, const float* __restrict__ xc,
        float* __restrict__ xdbl){
    const float* xw = F + OFF_XPW;
    int id = blockIdx.x;            // (b*K + k)*L + l
    int l = id % LL; int bk = id / LL; int k = bk % KK; int b = bk / KK;
    int s = sidx(k, l);
    __shared__ __align__(16) float row[DIN];
    int t = threadIdx.x;            // 0..63
    reinterpret_cast<float4*>(row)[t] =
        reinterpret_cast<const float4*>(xc + (b*LL + s)*DIN)[t];
    __syncthreads();
    if (t < CD){
        const float4* w4 = reinterpret_cast<const float4*>(xw + (k*CD + t)*DIN);
        const float4* r4 = reinterpret_cast<const float4*>(row);
        float acc = 0.f;
        #pragma unroll
        for (int c4 = 0; c4 < DIN/4; ++c4){
            float4 wv = w4[c4], xv = r4[c4];
            acc = fmaf(wv.x, xv.x, acc); acc = fmaf(wv.y, xv.y, acc);
            acc = fmaf(wv.z, xv.z, acc); acc = fmaf(wv.w, xv.w, acc);
        }
        xdbl[id*CD + t] = acc;
    }
}

// ---------------- Pass A: per-chunk local scan -> s_end, delta-sum ----------
__global__ __launch_bounds__(256) void k_scanA(
        const float* __restrict__ F, const float* __restrict__ xc,
        const float* __restrict__ xdbl,
        float* __restrict__ send, float* __restrict__ dsum){
    int id = blockIdx.x;            // (b*K + k)*PC + c
    int c = id % PC; int bk = id / PC; int k = bk % KK; int b = bk / KK;
    int d = threadIdx.x;
    __shared__ float4 rows4[LC*10];
    const float4* src4 = reinterpret_cast<const float4*>(xdbl + (size_t)id*LC*CD);
    for (int i = d; i < LC*10; i += 256) rows4[i] = src4[i];
    __syncthreads();

    const float* dtwp = F + OFF_DTW + (k*DIN + d)*RR;
    float dtw[RR];
    #pragma unroll
    for (int r = 0; r < RR; ++r) dtw[r] = dtwp[r];
    float dtb = F[OFF_DTB + k*DIN + d];
    const float* ap = F + OFF_ALG + (k*DIN + d)*NS;
    float aa[NS];
    #pragma unroll
    for (int n = 0; n < NS; ++n) aa[n] = -__expf(ap[n]);
    float st[NS];
    #pragma unroll
    for (int n = 0; n < NS; ++n) st[n] = 0.f;
    float cum = 0.f;

    for (int l = 0; l < LC; ++l){
        float4 q0 = rows4[l*10+0], q1 = rows4[l*10+1];
        float xdt = dtb;
        xdt = fmaf(q0.x, dtw[0], xdt); xdt = fmaf(q0.y, dtw[1], xdt);
        xdt = fmaf(q0.z, dtw[2], xdt); xdt = fmaf(q0.w, dtw[3], xdt);
        xdt = fmaf(q1.x, dtw[4], xdt); xdt = fmaf(q1.y, dtw[5], xdt);
        xdt = fmaf(q1.z, dtw[6], xdt); xdt = fmaf(q1.w, dtw[7], xdt);
        float delta = (xdt > 15.f) ? xdt : __logf(1.f + __expf(xdt));
        cum += delta;
        int gl = c*LC + l;
        float u = xc[(b*LL + sidx(k, gl))*DIN + d];
        float du = delta * u;
        float4 B0 = rows4[l*10+2], B1 = rows4[l*10+3], B2 = rows4[l*10+4], B3 = rows4[l*10+5];
        float bv[NS] = {B0.x,B0.y,B0.z,B0.w, B1.x,B1.y,B1.z,B1.w,
                        B2.x,B2.y,B2.z,B2.w, B3.x,B3.y,B3.z,B3.w};
        #pragma unroll
        for (int n = 0; n < NS; ++n){
            float dA = __expf(delta * aa[n]);
            st[n] = fmaf(dA, st[n], du * bv[n]);
        }
    }
    float4* so = reinterpret_cast<float4*>(send + ((size_t)id*DIN + d)*NS);
    #pragma unroll
    for (int n4 = 0; n4 < 4; ++n4)
        so[n4] = make_float4(st[n4*4], st[n4*4+1], st[n4*4+2], st[n4*4+3]);
    dsum[id*DIN + d] = cum;
}

// ---------------- Combine: sequential chunk-state composition (in place) ----
__global__ __launch_bounds__(256) void k_comb(
        const float* __restrict__ F,
        float* __restrict__ send, const float* __restrict__ dsum){
    int gid = blockIdx.x*256 + threadIdx.x;     // ((b*K+k)*DIN + d)*NS + n
    int n = gid & 15; int d = (gid >> 4) & 255; int bk = gid >> 12;
    int k = bk & 3;
    float A = -__expf(F[OFF_ALG + (k*DIN + d)*NS + n]);
    float init = 0.f;
    for (int c = 0; c < PC; ++c){
        size_t addr = (((size_t)(bk*PC + c))*DIN + d)*NS + n;
        float tmp = send[addr];
        send[addr] = init;                      // becomes s_init for chunk c
        init = fmaf(__expf(dsum[(bk*PC + c)*DIN + d] * A), init, tmp);
    }
}

// ---------------- Pass B: scan with true init, emit y (atomic dir-combine) --
__global__ __launch_bounds__(256) void k_scanB(
        const float* __restrict__ F, const float* __restrict__ xc,
        const float* __restrict__ xdbl,
        const float* __restrict__ sinit, float* __restrict__ y){
    int id = blockIdx.x;
    int c = id % PC; int bk = id / PC; int k = bk % KK; int b = bk / KK;
    int d = threadIdx.x;
    __shared__ float4 rows4[LC*10];
    const float4* src4 = reinterpret_cast<const float4*>(xdbl + (size_t)id*LC*CD);
    for (int i = d; i < LC*10; i += 256) rows4[i] = src4[i];
    __syncthreads();

    const float* dtwp = F + OFF_DTW + (k*DIN + d)*RR;
    float dtw[RR];
    #pragma unroll
    for (int r = 0; r < RR; ++r) dtw[r] = dtwp[r];
    float dtb = F[OFF_DTB + k*DIN + d];
    float Dd  = F[OFF_DSS + k*DIN + d];
    const float* ap = F + OFF_ALG + (k*DIN + d)*NS;
    float aa[NS];
    #pragma unroll
    for (int n = 0; n < NS; ++n) aa[n] = -__expf(ap[n]);
    float st[NS];
    const float4* si = reinterpret_cast<const float4*>(sinit + ((size_t)id*DIN + d)*NS);
    #pragma unroll
    for (int n4 = 0; n4 < 4; ++n4){
        float4 v = si[n4];
        st[n4*4] = v.x; st[n4*4+1] = v.y; st[n4*4+2] = v.z; st[n4*4+3] = v.w;
    }

    for (int l = 0; l < LC; ++l){
        float4 q0 = rows4[l*10+0], q1 = rows4[l*10+1];
        float xdt = dtb;
        xdt = fmaf(q0.x, dtw[0], xdt); xdt = fmaf(q0.y, dtw[1], xdt);
        xdt = fmaf(q0.z, dtw[2], xdt); xdt = fmaf(q0.w, dtw[3], xdt);
        xdt = fmaf(q1.x, dtw[4], xdt); xdt = fmaf(q1.y, dtw[5], xdt);
        xdt = fmaf(q1.z, dtw[6], xdt); xdt = fmaf(q1.w, dtw[7], xdt);
        float delta = (xdt > 15.f) ? xdt : __logf(1.f + __expf(xdt));
        int gl = c*LC + l;
        int s = sidx(k, gl);
        float u = xc[(b*LL + s)*DIN + d];
        float du = delta * u;
        float4 B0 = rows4[l*10+2], B1 = rows4[l*10+3], B2 = rows4[l*10+4], B3 = rows4[l*10+5];
        float4 C0 = rows4[l*10+6], C1 = rows4[l*10+7], C2 = rows4[l*10+8], C3 = rows4[l*10+9];
        float bv[NS] = {B0.x,B0.y,B0.z,B0.w, B1.x,B1.y,B1.z,B1.w,
                        B2.x,B2.y,B2.z,B2.w, B3.x,B3.y,B3.z,B3.w};
        float cv[NS] = {C0.x,C0.y,C0.z,C0.w, C1.x,C1.y,C1.z,C1.w,
                        C2.x,C2.y,C2.z,C2.w, C3.x,C3.y,C3.z,C3.w};
        float yv = Dd * u;
        #pragma unroll
        for (int n = 0; n < NS; ++n){
            float dA = __expf(delta * aa[n]);
            st[n] = fmaf(dA, st[n], du * bv[n]);
            yv = fmaf(st[n], cv[n], yv);
        }
        atomicAdd(&y[(b*LL + s)*DIN + d], yv);
    }
}

// ---------------- Final: LayerNorm * z, out_proj -> out (bf16 or fp32) ------
__global__ __launch_bounds__(256) void k_final(
        const float* __restrict__ F,
        const float* __restrict__ y, const float* __restrict__ z,
        const int* __restrict__ flag, void* __restrict__ out){
    const float* wn = F + OFF_ONW;
    const float* bn = F + OFF_ONB;
    const float* w2 = F + OFF_OPW;
    const float* b2 = F + OFF_OPB;
    int bl = blockIdx.x;
    int t  = threadIdx.x;           // 0..255 = d
    __shared__ __align__(16) float yn[DIN];
    __shared__ float red[8];
    float v = y[bl*DIN + t];
    float s1 = v, s2 = v*v;
    #pragma unroll
    for (int o = 32; o > 0; o >>= 1){
        s1 += __shfl_down(s1, o);
        s2 += __shfl_down(s2, o);
    }
    if ((t & 63) == 0){ red[t >> 6] = s1; red[4 + (t >> 6)] = s2; }
    __syncthreads();
    float sum  = red[0] + red[1] + red[2] + red[3];
    float sumq = red[4] + red[5] + red[6] + red[7];
    float mu = sum * (1.f/DIN);
    float var = fmaxf(sumq * (1.f/DIN) - mu*mu, 0.f);
    float rstd = rsqrtf(var + 1e-5f);
    yn[t] = ((v - mu) * rstd * wn[t] + bn[t]) * z[bl*DIN + t];
    __syncthreads();
    if (t < C_){
        const float4* w4 = reinterpret_cast<const float4*>(w2 + t*DIN);
        const float4* r4 = reinterpret_cast<const float4*>(yn);
        float acc = b2[t];
        #pragma unroll
        for (int c4 = 0; c4 < DIN/4; ++c4){
            float4 wv = w4[c4], xv = r4[c4];
            acc = fmaf(wv.x, xv.x, acc); acc = fmaf(wv.y, xv.y, acc);
            acc = fmaf(wv.z, xv.z, acc); acc = fmaf(wv.w, xv.w, acc);
        }
        if (*flag) ((float*)out)[bl*C_ + t] = acc;
        else       ((unsigned short*)out)[bl*C_ + t] = f2bf(acc);
    }
}

extern "C" void kernel_launch(void* const* d_in, const int* in_sizes, int n_in,
                              void* d_out, int out_size, void* d_ws, size_t ws_size,
                              hipStream_t stream){
    float* ws   = (float*)d_ws;
    float* F    = ws;
    float* xc   = ws + WOFF_XC;
    float* z    = ws + WOFF_Z;
    float* y    = ws + WOFF_Y;
    float* xdbl = ws + WOFF_XDBL;
    float* send = ws + WOFF_SEND;
    float* dsum = ws + WOFF_DSUM;
    float* xh   = ws + WOFF_SEND;   // alias: xh dead before send is written
    int*   flag = (int*)(ws + WOFF_FLAG);

    CvtArgs a;
    for (int i = 0; i < 14; ++i) a.src[i] = d_in[i];
    const int offs[15] = {OFF_X, OFF_IPW, OFF_IPB, OFF_CW, OFF_CB, OFF_XPW,
                          OFF_DTW, OFF_DTB, OFF_ALG, OFF_DSS, OFF_ONW, OFF_ONB,
                          OFF_OPW, OFF_OPB, F_TOTAL};
    for (int i = 0; i < 15; ++i) a.off[i] = offs[i];

    k_detect <<<1, 256, 0, stream>>>((const unsigned short*)d_in[0], flag);
    k_convert<<<(F_TOTAL + 255)/256, 256, 0, stream>>>(a, flag, F);
    k_inproj <<<B_*LL, 512, 0, stream>>>(F, xh, z);
    k_conv   <<<B_*LL, 256, 0, stream>>>(F, xh, xc);
    hipMemsetAsync(y, 0, (size_t)B_*LL*DIN*sizeof(float), stream);
    k_xproj  <<<B_*KK*LL, 64, 0, stream>>>(F, xc, xdbl);
    k_scanA  <<<B_*KK*PC, 256, 0, stream>>>(F, xc, xdbl, send, dsum);
    k_comb   <<<(B_*KK*DIN*NS)/256, 256, 0, stream>>>(F, send, dsum);
    k_scanB  <<<B_*KK*PC, 256, 0, stream>>>(F, xc, xdbl, send, y);
    k_final  <<<B_*LL, 256, 0, stream>>>(F, y, z, flag, d_out);
}

// Round 3
// 263.864 us; speedup vs baseline: 2.3284x; 2.3284x over previous
//
#include <hip/hip_runtime.h>

// SS2D (VMamba selective scan 2D), dtype-robust (bf16 or fp32 inputs/outputs).
// All intermediates fp32 in d_ws. ws usage: 9,021,060 floats = 36.1 MB.
#define B_  2
#define H_  56
#define W_  56
#define C_  128
#define DIN 256
#define NS  16
#define RR  8
#define KK  4
#define LL  3136
#define CD  40      // R + 2N
#define PC  64      // scan chunks
#define LC  49      // L / PC

// converted-input (fp32) region offsets, cumulative, in floats
#define OFF_X    0
#define OFF_IPW  802816
#define OFF_IPB  868352
#define OFF_CW   868864
#define OFF_CB   871168
#define OFF_XPW  871424
#define OFF_DTW  912384
#define OFF_DTB  920576
#define OFF_ALG  921600
#define OFF_DSS  937984
#define OFF_ONW  939008
#define OFF_ONB  939264
#define OFF_OPW  939520
#define OFF_OPB  972288
#define F_TOTAL  972416

// workspace regions, in floats
#define WOFF_XC    972416       // 1,605,632 (later reused as yn)
#define WOFF_Z     2578048      // 1,605,632
#define WOFF_Y     4183680      // 1,605,632
#define WOFF_XDBL  5789312      // 1,003,520
#define WOFF_SEND  6792832      // 2,097,152 (xh aliases this region)
#define WOFF_DSUM  8889984      //   131,072
#define WOFF_FLAG  9021056      // 1 int

__device__ __forceinline__ float bf2f(unsigned int h){
    return __uint_as_float((h & 0xffffu) << 16);
}
__device__ __forceinline__ unsigned short f2bf(float f){
    unsigned int u = __float_as_uint(f);
    u += 0x7fffu + ((u >> 16) & 1u);
    return (unsigned short)(u >> 16);
}
__device__ __forceinline__ float siluf(float x){ return x / (1.f + __expf(-x)); }

// scan-order -> spatial index
__device__ __forceinline__ int sidx(int k, int l){
    int j = (k < 2) ? l : (LL - 1 - l);
    if ((k & 1) == 0) return j;                 // row-major scan
    return (j % H_) * W_ + (j / H_);            // col-major scan
}

// ---------------- K0a: detect input dtype ----------------------------------
__global__ void k_detect(const unsigned short* __restrict__ x, int* __restrict__ flag){
    __shared__ float m[256];
    int t = threadIdx.x;
    m[t] = fabsf(bf2f(x[t]));
    __syncthreads();
    if (t == 0){
        float mx = 0.f;
        for (int i = 0; i < 256; ++i) mx = fmaxf(mx, m[i]);
        *flag = (mx > 1e6f) ? 1 : 0;
    }
}

// ---------------- K0b: convert all inputs to fp32 region F ------------------
struct CvtArgs { const void* src[14]; int off[15]; };

__global__ __launch_bounds__(256) void k_convert(CvtArgs a, const int* __restrict__ flag,
                                                 float* __restrict__ F){
    int g = blockIdx.x*256 + threadIdx.x;
    if (g >= F_TOTAL) return;
    int seg = 0;
    #pragma unroll
    for (int i = 1; i < 14; ++i) seg += (g >= a.off[i]);
    int i0 = g - a.off[seg];
    float v;
    if (*flag) v = ((const float*)a.src[seg])[i0];
    else       v = bf2f(((const unsigned short*)a.src[seg])[i0]);
    F[g] = v;
}

// ---------------- K1: in_proj as tiled GEMM: [6272x128]x[128x512] ----------
// 64x64 tile, K=128 single stage, 4x4 micro-tile. LDS 64 KB -> 2 blocks/CU.
__global__ __launch_bounds__(256) void k_gemm_in(
        const float* __restrict__ F, float* __restrict__ xh, float* __restrict__ z){
    __shared__ __align__(16) float As[128*64];
    __shared__ __align__(16) float Bs[128*64];
    int nt = blockIdx.x & 7, mt = blockIdx.x >> 3;   // 8 x 98
    int t = threadIdx.x;
    const float4* A4 = reinterpret_cast<const float4*>(F + OFF_X);
    const float4* B4 = reinterpret_cast<const float4*>(F + OFF_IPW);
    int m = t & 63, kkb = (t >> 6) * 8;
    #pragma unroll
    for (int j = 0; j < 8; ++j){
        int kk = kkb + j;                             // 0..31 (float4 along K)
        float4 va = A4[(mt*64 + m)*32 + kk];
        As[(kk*4+0)*64 + m] = va.x; As[(kk*4+1)*64 + m] = va.y;
        As[(kk*4+2)*64 + m] = va.z; As[(kk*4+3)*64 + m] = va.w;
        float4 vb = B4[(nt*64 + m)*32 + kk];          // m doubles as n here
        Bs[(kk*4+0)*64 + m] = vb.x; Bs[(kk*4+1)*64 + m] = vb.y;
        Bs[(kk*4+2)*64 + m] = vb.z; Bs[(kk*4+3)*64 + m] = vb.w;
    }
    __syncthreads();
    int tm = t & 15, tn = t >> 4;
    float acc[4][4];
    #pragma unroll
    for (int i = 0; i < 4; ++i)
        #pragma unroll
        for (int j = 0; j < 4; ++j) acc[i][j] = 0.f;
    #pragma unroll 8
    for (int k = 0; k < 128; ++k){
        float4 av = *reinterpret_cast<const float4*>(As + k*64 + tm*4);
        float4 bv = *reinterpret_cast<const float4*>(Bs + k*64 + tn*4);
        acc[0][0]=fmaf(av.x,bv.x,acc[0][0]); acc[0][1]=fmaf(av.x,bv.y,acc[0][1]);
        acc[0][2]=fmaf(av.x,bv.z,acc[0][2]); acc[0][3]=fmaf(av.x,bv.w,acc[0][3]);
        acc[1][0]=fmaf(av.y,bv.x,acc[1][0]); acc[1][1]=fmaf(av.y,bv.y,acc[1][1]);
        acc[1][2]=fmaf(av.y,bv.z,acc[1][2]); acc[1][3]=fmaf(av.y,bv.w,acc[1][3]);
        acc[2][0]=fmaf(av.z,bv.x,acc[2][0]); acc[2][1]=fmaf(av.z,bv.y,acc[2][1]);
        acc[2][2]=fmaf(av.z,bv.z,acc[2][2]); acc[2][3]=fmaf(av.z,bv.w,acc[2][3]);
        acc[3][0]=fmaf(av.w,bv.x,acc[3][0]); acc[3][1]=fmaf(av.w,bv.y,acc[3][1]);
        acc[3][2]=fmaf(av.w,bv.z,acc[3][2]); acc[3][3]=fmaf(av.w,bv.w,acc[3][3]);
    }
    int ngl = nt*64 + tn*4;
    float4 bias = *reinterpret_cast<const float4*>(F + OFF_IPB + ngl);
    #pragma unroll
    for (int i = 0; i < 4; ++i){
        int bl = mt*64 + tm*4 + i;
        float4 r;
        r.x = acc[i][0] + bias.x; r.y = acc[i][1] + bias.y;
        r.z = acc[i][2] + bias.z; r.w = acc[i][3] + bias.w;
        if (nt < 4){
            *reinterpret_cast<float4*>(xh + (size_t)bl*DIN + ngl) = r;
        } else {
            float4 s;
            s.x = siluf(r.x); s.y = siluf(r.y); s.z = siluf(r.z); s.w = siluf(r.w);
            *reinterpret_cast<float4*>(z + (size_t)bl*DIN + (ngl - DIN)) = s;
        }
    }
}

// ---------------- K2: depthwise 3x3 conv + silu, sliding window -------------
#define CSPLIT 4
#define CCOLS  14   // 56 / CSPLIT
__global__ __launch_bounds__(256) void k_conv(
        const float* __restrict__ F, const float* __restrict__ xh,
        float* __restrict__ xc){
    int bi = blockIdx.x;
    int sw = bi & 3; int h = (bi >> 2) % H_; int b = bi / (H_*CSPLIT);
    int d = threadIdx.x;
    float cwv[9];
    #pragma unroll
    for (int i = 0; i < 9; ++i) cwv[i] = F[OFF_CW + d*9 + i];
    float bias = F[OFF_CB + d];
    const float* base[3];
    bool rv[3];
    #pragma unroll
    for (int i = 0; i < 3; ++i){
        int nh = h - 1 + i;
        rv[i] = (nh >= 0 && nh < H_);
        base[i] = xh + ((size_t)b*LL + (rv[i] ? nh : 0)*W_)*DIN + d;
    }
    int w0 = sw*CCOLS;
    float a0,a1,a2, b0,b1,b2, c0,c1,c2;
    a0 = (w0 > 0 && rv[0]) ? base[0][(w0-1)*DIN] : 0.f;
    a1 = (w0 > 0 && rv[1]) ? base[1][(w0-1)*DIN] : 0.f;
    a2 = (w0 > 0 && rv[2]) ? base[2][(w0-1)*DIN] : 0.f;
    b0 = rv[0] ? base[0][w0*DIN] : 0.f;
    b1 = rv[1] ? base[1][w0*DIN] : 0.f;
    b2 = rv[2] ? base[2][w0*DIN] : 0.f;
    for (int w = w0; w < w0 + CCOLS; ++w){
        bool cin = (w + 1 < W_);
        c0 = (cin && rv[0]) ? base[0][(w+1)*DIN] : 0.f;
        c1 = (cin && rv[1]) ? base[1][(w+1)*DIN] : 0.f;
        c2 = (cin && rv[2]) ? base[2][(w+1)*DIN] : 0.f;
        float acc = bias;
        acc = fmaf(a0, cwv[0], acc); acc = fmaf(b0, cwv[1], acc); acc = fmaf(c0, cwv[2], acc);
        acc = fmaf(a1, cwv[3], acc); acc = fmaf(b1, cwv[4], acc); acc = fmaf(c1, cwv[5], acc);
        acc = fmaf(a2, cwv[6], acc); acc = fmaf(b2, cwv[7], acc); acc = fmaf(c2, cwv[8], acc);
        xc[((size_t)b*LL + h*W_ + w)*DIN + d] = siluf(acc);
        a0=b0; a1=b1; a2=b2; b0=c0; b1=c1; b2=c2;
    }
}

// ---------------- K3: x_proj as tiled GEMM (row-gathered A) -----------------
// per (b,dir): [3136 x 256] x [256 x 40->48pad], 64-row tiles, K in 2 stages.
__global__ __launch_bounds__(256) void k_gemm_xp(
        const float* __restrict__ F, const float* __restrict__ xc,
        float* __restrict__ xdbl){
    __shared__ __align__(16) float As[128*64];
    __shared__ __align__(16) float Bs[128*49];
    int bi = blockIdx.x;                 // 2*4*49
    int lt = bi % 49; int dir = (bi / 49) & 3; int b = bi / 196;
    int t = threadIdx.x;
    const float4* X4 = reinterpret_cast<const float4*>(xc);
    const float4* W4 = reinterpret_cast<const float4*>(F + OFF_XPW);
    int tm = t & 15, tn = t >> 4;
    float acc[4][3];
    #pragma unroll
    for (int i = 0; i < 4; ++i){ acc[i][0]=0.f; acc[i][1]=0.f; acc[i][2]=0.f; }

    for (int kc = 0; kc < 2; ++kc){
        int m = t & 63, kkb = (t >> 6) * 8;
        int l = lt*64 + m;
        int srow = b*LL + sidx(dir, l);
        #pragma unroll
        for (int j = 0; j < 8; ++j){
            int kk = kkb + j;
            float4 va = X4[(size_t)srow*64 + kc*32 + kk];
            As[(kk*4+0)*64 + m] = va.x; As[(kk*4+1)*64 + m] = va.y;
            As[(kk*4+2)*64 + m] = va.z; As[(kk*4+3)*64 + m] = va.w;
            if (m < CD){
                float4 vb = W4[((size_t)dir*CD + m)*64 + kc*32 + kk];
                Bs[(kk*4+0)*49 + m] = vb.x; Bs[(kk*4+1)*49 + m] = vb.y;
                Bs[(kk*4+2)*49 + m] = vb.z; Bs[(kk*4+3)*49 + m] = vb.w;
            } else if (m < 48){
                Bs[(kk*4+0)*49 + m] = 0.f; Bs[(kk*4+1)*49 + m] = 0.f;
                Bs[(kk*4+2)*49 + m] = 0.f; Bs[(kk*4+3)*49 + m] = 0.f;
            }
        }
        __syncthreads();
        #pragma unroll 8
        for (int k = 0; k < 128; ++k){
            float4 av = *reinterpret_cast<const float4*>(As + k*64 + tm*4);
            float b0 = Bs[k*49 + tn*3 + 0];
            float b1 = Bs[k*49 + tn*3 + 1];
            float b2 = Bs[k*49 + tn*3 + 2];
            acc[0][0]=fmaf(av.x,b0,acc[0][0]); acc[0][1]=fmaf(av.x,b1,acc[0][1]); acc[0][2]=fmaf(av.x,b2,acc[0][2]);
            acc[1][0]=fmaf(av.y,b0,acc[1][0]); acc[1][1]=fmaf(av.y,b1,acc[1][1]); acc[1][2]=fmaf(av.y,b2,acc[1][2]);
            acc[2][0]=fmaf(av.z,b0,acc[2][0]); acc[2][1]=fmaf(av.z,b1,acc[2][1]); acc[2][2]=fmaf(av.z,b2,acc[2][2]);
            acc[3][0]=fmaf(av.w,b0,acc[3][0]); acc[3][1]=fmaf(av.w,b1,acc[3][1]); acc[3][2]=fmaf(av.w,b2,acc[3][2]);
        }
        __syncthreads();
    }
    size_t orow = ((size_t)(b*KK + dir)*LL + lt*64);
    #pragma unroll
    for (int i = 0; i < 4; ++i){
        int lrow = tm*4 + i;
        #pragma unroll
        for (int j = 0; j < 3; ++j){
            int n = tn*3 + j;
            if (n < CD) xdbl[(orow + lrow)*CD + n] = acc[i][j];
        }
    }
}

// ---------------- Pass A: per-chunk local scan -> s_end, delta-sum ----------
__global__ __launch_bounds__(256) void k_scanA(
        const float* __restrict__ F, const float* __restrict__ xc,
        const float* __restrict__ xdbl,
        float* __restrict__ send, float* __restrict__ dsum){
    int id = blockIdx.x;            // (b*K + k)*PC + c
    int c = id % PC; int bk = id / PC; int k = bk % KK; int b = bk / KK;
    int d = threadIdx.x;
    __shared__ float4 rows4[LC*10];
    const float4* src4 = reinterpret_cast<const float4*>(xdbl + (size_t)id*LC*CD);
    for (int i = d; i < LC*10; i += 256) rows4[i] = src4[i];
    __syncthreads();

    const float* dtwp = F + OFF_DTW + (k*DIN + d)*RR;
    float dtw[RR];
    #pragma unroll
    for (int r = 0; r < RR; ++r) dtw[r] = dtwp[r];
    float dtb = F[OFF_DTB + k*DIN + d];
    const float* ap = F + OFF_ALG + (k*DIN + d)*NS;
    float aa[NS];
    #pragma unroll
    for (int n = 0; n < NS; ++n) aa[n] = -__expf(ap[n]);
    float st[NS];
    #pragma unroll
    for (int n = 0; n < NS; ++n) st[n] = 0.f;
    float cum = 0.f;

    for (int l = 0; l < LC; ++l){
        float4 q0 = rows4[l*10+0], q1 = rows4[l*10+1];
        float xdt = dtb;
        xdt = fmaf(q0.x, dtw[0], xdt); xdt = fmaf(q0.y, dtw[1], xdt);
        xdt = fmaf(q0.z, dtw[2], xdt); xdt = fmaf(q0.w, dtw[3], xdt);
        xdt = fmaf(q1.x, dtw[4], xdt); xdt = fmaf(q1.y, dtw[5], xdt);
        xdt = fmaf(q1.z, dtw[6], xdt); xdt = fmaf(q1.w, dtw[7], xdt);
        float delta = (xdt > 15.f) ? xdt : __logf(1.f + __expf(xdt));
        cum += delta;
        int gl = c*LC + l;
        float u = xc[((size_t)b*LL + sidx(k, gl))*DIN + d];
        float du = delta * u;
        float4 B0 = rows4[l*10+2], B1 = rows4[l*10+3], B2 = rows4[l*10+4], B3 = rows4[l*10+5];
        float bv[NS] = {B0.x,B0.y,B0.z,B0.w, B1.x,B1.y,B1.z,B1.w,
                        B2.x,B2.y,B2.z,B2.w, B3.x,B3.y,B3.z,B3.w};
        #pragma unroll
        for (int n = 0; n < NS; ++n){
            float dA = __expf(delta * aa[n]);
            st[n] = fmaf(dA, st[n], du * bv[n]);
        }
    }
    float4* so = reinterpret_cast<float4*>(send + ((size_t)id*DIN + d)*NS);
    #pragma unroll
    for (int n4 = 0; n4 < 4; ++n4)
        so[n4] = make_float4(st[n4*4], st[n4*4+1], st[n4*4+2], st[n4*4+3]);
    dsum[id*DIN + d] = cum;
}

// ---------------- Combine: sequential chunk-state composition (in place) ----
__global__ __launch_bounds__(256) void k_comb(
        const float* __restrict__ F,
        float* __restrict__ send, const float* __restrict__ dsum){
    int gid = blockIdx.x*256 + threadIdx.x;     // ((b*K+k)*DIN + d)*NS + n
    int n = gid & 15; int d = (gid >> 4) & 255; int bk = gid >> 12;
    int k = bk & 3;
    float A = -__expf(F[OFF_ALG + (k*DIN + d)*NS + n]);
    float init = 0.f;
    for (int c = 0; c < PC; ++c){
        size_t addr = (((size_t)(bk*PC + c))*DIN + d)*NS + n;
        float tmp = send[addr];
        send[addr] = init;                      // becomes s_init for chunk c
        init = fmaf(__expf(dsum[(bk*PC + c)*DIN + d] * A), init, tmp);
    }
}

// ---------------- Pass B: scan with true init, emit y (atomic dir-combine) --
__global__ __launch_bounds__(256) void k_scanB(
        const float* __restrict__ F, const float* __restrict__ xc,
        const float* __restrict__ xdbl,
        const float* __restrict__ sinit, float* __restrict__ y){
    int id = blockIdx.x;
    int c = id % PC; int bk = id / PC; int k = bk % KK; int b = bk / KK;
    int d = threadIdx.x;
    __shared__ float4 rows4[LC*10];
    const float4* src4 = reinterpret_cast<const float4*>(xdbl + (size_t)id*LC*CD);
    for (int i = d; i < LC*10; i += 256) rows4[i] = src4[i];
    __syncthreads();

    const float* dtwp = F + OFF_DTW + (k*DIN + d)*RR;
    float dtw[RR];
    #pragma unroll
    for (int r = 0; r < RR; ++r) dtw[r] = dtwp[r];
    float dtb = F[OFF_DTB + k*DIN + d];
    float Dd  = F[OFF_DSS + k*DIN + d];
    const float* ap = F + OFF_ALG + (k*DIN + d)*NS;
    float aa[NS];
    #pragma unroll
    for (int n = 0; n < NS; ++n) aa[n] = -__expf(ap[n]);
    float st[NS];
    const float4* si = reinterpret_cast<const float4*>(sinit + ((size_t)id*DIN + d)*NS);
    #pragma unroll
    for (int n4 = 0; n4 < 4; ++n4){
        float4 v = si[n4];
        st[n4*4] = v.x; st[n4*4+1] = v.y; st[n4*4+2] = v.z; st[n4*4+3] = v.w;
    }

    for (int l = 0; l < LC; ++l){
        float4 q0 = rows4[l*10+0], q1 = rows4[l*10+1];
        float xdt = dtb;
        xdt = fmaf(q0.x, dtw[0], xdt); xdt = fmaf(q0.y, dtw[1], xdt);
        xdt = fmaf(q0.z, dtw[2], xdt); xdt = fmaf(q0.w, dtw[3], xdt);
        xdt = fmaf(q1.x, dtw[4], xdt); xdt = fmaf(q1.y, dtw[5], xdt);
        xdt = fmaf(q1.z, dtw[6], xdt); xdt = fmaf(q1.w, dtw[7], xdt);
        float delta = (xdt > 15.f) ? xdt : __logf(1.f + __expf(xdt));
        int gl = c*LC + l;
        int s = sidx(k, gl);
        float u = xc[((size_t)b*LL + s)*DIN + d];
        float du = delta * u;
        float4 B0 = rows4[l*10+2], B1 = rows4[l*10+3], B2 = rows4[l*10+4], B3 = rows4[l*10+5];
        float4 C0 = rows4[l*10+6], C1 = rows4[l*10+7], C2 = rows4[l*10+8], C3 = rows4[l*10+9];
        float bv[NS] = {B0.x,B0.y,B0.z,B0.w, B1.x,B1.y,B1.z,B1.w,
                        B2.x,B2.y,B2.z,B2.w, B3.x,B3.y,B3.z,B3.w};
        float cv[NS] = {C0.x,C0.y,C0.z,C0.w, C1.x,C1.y,C1.z,C1.w,
                        C2.x,C2.y,C2.z,C2.w, C3.x,C3.y,C3.z,C3.w};
        float yv = Dd * u;
        #pragma unroll
        for (int n = 0; n < NS; ++n){
            float dA = __expf(delta * aa[n]);
            st[n] = fmaf(dA, st[n], du * bv[n]);
            yv = fmaf(st[n], cv[n], yv);
        }
        atomicAdd(&y[((size_t)b*LL + s)*DIN + d], yv);
    }
}

// ---------------- LayerNorm * z -> yn ---------------------------------------
__global__ __launch_bounds__(256) void k_ln(
        const float* __restrict__ F,
        const float* __restrict__ y, const float* __restrict__ z,
        float* __restrict__ yn){
    int bl = blockIdx.x;
    int t  = threadIdx.x;
    __shared__ float red[8];
    float v = y[(size_t)bl*DIN + t];
    float s1 = v, s2 = v*v;
    #pragma unroll
    for (int o = 32; o > 0; o >>= 1){
        s1 += __shfl_down(s1, o);
        s2 += __shfl_down(s2, o);
    }
    if ((t & 63) == 0){ red[t >> 6] = s1; red[4 + (t >> 6)] = s2; }
    __syncthreads();
    float sum  = red[0] + red[1] + red[2] + red[3];
    float sumq = red[4] + red[5] + red[6] + red[7];
    float mu = sum * (1.f/DIN);
    float var = fmaxf(sumq * (1.f/DIN) - mu*mu, 0.f);
    float rstd = rsqrtf(var + 1e-5f);
    yn[(size_t)bl*DIN + t] =
        ((v - mu) * rstd * F[OFF_ONW + t] + F[OFF_ONB + t]) * z[(size_t)bl*DIN + t];
}

// ---------------- out_proj as tiled GEMM: [6272x256]x[256x128] --------------
__global__ __launch_bounds__(256) void k_gemm_out(
        const float* __restrict__ F, const float* __restrict__ yn,
        const int* __restrict__ flag, void* __restrict__ out){
    __shared__ __align__(16) float As[128*64];
    __shared__ __align__(16) float Bs[128*64];
    int nt = blockIdx.x & 1, mt = blockIdx.x >> 1;   // 2 x 98
    int t = threadIdx.x;
    const float4* A4 = reinterpret_cast<const float4*>(yn);
    const float4* B4 = reinterpret_cast<const float4*>(F + OFF_OPW);
    int tm = t & 15, tn = t >> 4;
    float acc[4][4];
    #pragma unroll
    for (int i = 0; i < 4; ++i)
        #pragma unroll
        for (int j = 0; j < 4; ++j) acc[i][j] = 0.f;

    for (int kc = 0; kc < 2; ++kc){
        int m = t & 63, kkb = (t >> 6) * 8;
        #pragma unroll
        for (int j = 0; j < 8; ++j){
            int kk = kkb + j;
            float4 va = A4[((size_t)mt*64 + m)*64 + kc*32 + kk];
            As[(kk*4+0)*64 + m] = va.x; As[(kk*4+1)*64 + m] = va.y;
            As[(kk*4+2)*64 + m] = va.z; As[(kk*4+3)*64 + m] = va.w;
            float4 vb = B4[((size_t)nt*64 + m)*64 + kc*32 + kk];
            Bs[(kk*4+0)*64 + m] = vb.x; Bs[(kk*4+1)*64 + m] = vb.y;
            Bs[(kk*4+2)*64 + m] = vb.z; Bs[(kk*4+3)*64 + m] = vb.w;
        }
        __syncthreads();
        #pragma unroll 8
        for (int k = 0; k < 128; ++k){
            float4 av = *reinterpret_cast<const float4*>(As + k*64 + tm*4);
            float4 bv = *reinterpret_cast<const float4*>(Bs + k*64 + tn*4);
            acc[0][0]=fmaf(av.x,bv.x,acc[0][0]); acc[0][1]=fmaf(av.x,bv.y,acc[0][1]);
            acc[0][2]=fmaf(av.x,bv.z,acc[0][2]); acc[0][3]=fmaf(av.x,bv.w,acc[0][3]);
            acc[1][0]=fmaf(av.y,bv.x,acc[1][0]); acc[1][1]=fmaf(av.y,bv.y,acc[1][1]);
            acc[1][2]=fmaf(av.y,bv.z,acc[1][2]); acc[1][3]=fmaf(av.y,bv.w,acc[1][3]);
            acc[2][0]=fmaf(av.z,bv.x,acc[2][0]); acc[2][1]=fmaf(av.z,bv.y,acc[2][1]);
            acc[2][2]=fmaf(av.z,bv.z,acc[2][2]); acc[2][3]=fmaf(av.z,bv.w,acc[2][3]);
            acc[3][0]=fmaf(av.w,bv.x,acc[3][0]); acc[3][1]=fmaf(av.w,bv.y,acc[3][1]);
            acc[3][2]=fmaf(av.w,bv.z,acc[3][2]); acc[3][3]=fmaf(av.w,bv.w,acc[3][3]);
        }
        __syncthreads();
    }
    int ngl = nt*64 + tn*4;
    float4 bias = *reinterpret_cast<const float4*>(F + OFF_OPB + ngl);
    int fl = *flag;
    #pragma unroll
    for (int i = 0; i < 4; ++i){
        int bl = mt*64 + tm*4 + i;
        float r0 = acc[i][0] + bias.x, r1 = acc[i][1] + bias.y;
        float r2 = acc[i][2] + bias.z, r3 = acc[i][3] + bias.w;
        if (fl){
            float4 r; r.x=r0; r.y=r1; r.z=r2; r.w=r3;
            *reinterpret_cast<float4*>((float*)out + (size_t)bl*C_ + ngl) = r;
        } else {
            unsigned short* o = (unsigned short*)out + (size_t)bl*C_ + ngl;
            o[0]=f2bf(r0); o[1]=f2bf(r1); o[2]=f2bf(r2); o[3]=f2bf(r3);
        }
    }
}

extern "C" void kernel_launch(void* const* d_in, const int* in_sizes, int n_in,
                              void* d_out, int out_size, void* d_ws, size_t ws_size,
                              hipStream_t stream){
    float* ws   = (float*)d_ws;
    float* F    = ws;
    float* xc   = ws + WOFF_XC;
    float* z    = ws + WOFF_Z;
    float* y    = ws + WOFF_Y;
    float* xdbl = ws + WOFF_XDBL;
    float* send = ws + WOFF_SEND;
    float* dsum = ws + WOFF_DSUM;
    float* xh   = ws + WOFF_SEND;   // alias: xh dead before send is written
    float* yn   = ws + WOFF_XC;     // alias: xc dead after scanB
    int*   flag = (int*)(ws + WOFF_FLAG);

    CvtArgs a;
    for (int i = 0; i < 14; ++i) a.src[i] = d_in[i];
    const int offs[15] = {OFF_X, OFF_IPW, OFF_IPB, OFF_CW, OFF_CB, OFF_XPW,
                          OFF_DTW, OFF_DTB, OFF_ALG, OFF_DSS, OFF_ONW, OFF_ONB,
                          OFF_OPW, OFF_OPB, F_TOTAL};
    for (int i = 0; i < 15; ++i) a.off[i] = offs[i];

    k_detect  <<<1, 256, 0, stream>>>((const unsigned short*)d_in[0], flag);
    k_convert <<<(F_TOTAL + 255)/256, 256, 0, stream>>>(a, flag, F);
    k_gemm_in <<<98*8, 256, 0, stream>>>(F, xh, z);
    k_conv    <<<B_*H_*CSPLIT, 256, 0, stream>>>(F, xh, xc);
    hipMemsetAsync(y, 0, (size_t)B_*LL*DIN*sizeof(float), stream);
    k_gemm_xp <<<B_*KK*49, 256, 0, stream>>>(F, xc, xdbl);
    k_scanA   <<<B_*KK*PC, 256, 0, stream>>>(F, xc, xdbl, send, dsum);
    k_comb    <<<(B_*KK*DIN*NS)/256, 256, 0, stream>>>(F, send, dsum);
    k_scanB   <<<B_*KK*PC, 256, 0, stream>>>(F, xc, xdbl, send, y);
    k_ln      <<<B_*LL, 256, 0, stream>>>(F, y, z, yn);
    k_gemm_out<<<98*2, 256, 0, stream>>>(F, yn, flag, d_out);
}